// Round 6
// baseline (327.385 us; speedup 1.0000x reference)
//
#include <hip/hip_runtime.h>

// Linear-chain CRF marginals, L = 4M, 2 labels.
// 3-pass parallel associative scan in the log semiring (2x2 log-matmuls).
// Carries in double, transcendentals in fp32 (abs err ~1e-7/step since the
// LSE correction is O(1); large magnitudes live exactly in the double part).

#define N_LEN      4194304
#define S_CHUNK    64
#define N_CHUNKS   (N_LEN / S_CHUNK)        // 65536
#define P1_BLOCK   256
#define P2_THREADS 1024
#define P2_G       (N_CHUNKS / P2_THREADS)  // 64

__device__ __forceinline__ double lse2d(double x, double y) {
    double mx = fmax(x, y);
    double d  = fmin(x, y) - mx;            // <= 0, O(1) magnitude
    float  c  = __logf(1.0f + __expf((float)d));
    return mx + (double)c;
}

struct DMat { double m00, m01, m10, m11; }; // M[i][j], row i, col j

__device__ __forceinline__ DMat logmm(const DMat X, const DMat Y) {
    // (X (x) Y)[i][j] = LSE_p(X[i][p] + Y[p][j])
    DMat R;
    R.m00 = lse2d(X.m00 + Y.m00, X.m01 + Y.m10);
    R.m01 = lse2d(X.m00 + Y.m01, X.m01 + Y.m11);
    R.m10 = lse2d(X.m10 + Y.m00, X.m11 + Y.m10);
    R.m11 = lse2d(X.m10 + Y.m01, X.m11 + Y.m11);
    return R;
}

// ---------------------------------------------------------------------------
// Pass 1 (fused fwd+bwd): per-chunk composed matrices, one thread per chunk.
// fwd: F_c = A_hi (x) ... (x) A_lo,  lo = c*S+1, hi = min((c+1)*S, N-1)
//   A_j[n][p] = f_j[n] + T[n][p];  F_c maps alpha_{c*S} -> alpha_hi
// bwd: B_c = B_lo' (x) ... (x) B_hi', lo' = max(c*S-1,0), hi' = (c+1)*S-2
//   B_j[p][n] = f_j[p] + T[n][p];  beta_{c*S-1} = B_c (x) beta_{(c+1)*S-1}
// Both compose left-to-right over increasing j; one feats read serves both,
// and the 8 independent lse chains give 2x the ILP of split kernels.
// ---------------------------------------------------------------------------
__global__ __launch_bounds__(P1_BLOCK) void crf_pass1(
    const float* __restrict__ feats, const float* __restrict__ trans,
    DMat* __restrict__ fwdmat, DMat* __restrict__ bwdmat)
{
    const int c = blockIdx.x * blockDim.x + threadIdx.x;
    const double t00 = trans[0], t01 = trans[1], t10 = trans[2], t11 = trans[3];

    const int lo_f = c * S_CHUNK + 1;
    const int hi_f = min((c + 1) * S_CHUNK, N_LEN - 1);
    const int lo_b = max(c * S_CHUNK - 1, 0);
    const int hi_b = (c + 1) * S_CHUNK - 2;

    DMat F, B;
    for (int j = lo_b; j <= hi_f; ++j) {
        float2 f = *(const float2*)(feats + 2 * j);
        const double fx = f.x, fy = f.y;
        // backward operator B_j[p][n] = f_j[p] + T[n][p]
        if (j == lo_b) {
            B.m00 = fx + t00; B.m01 = fx + t10;
            B.m10 = fy + t01; B.m11 = fy + t11;
        } else if (j <= hi_b) {
            double b00 = fx + t00, b01 = fx + t10;
            double b10 = fy + t01, b11 = fy + t11;
            double n00 = lse2d(B.m00 + b00, B.m01 + b10);
            double n01 = lse2d(B.m00 + b01, B.m01 + b11);
            double n10 = lse2d(B.m10 + b00, B.m11 + b10);
            double n11 = lse2d(B.m10 + b01, B.m11 + b11);
            B.m00 = n00; B.m01 = n01; B.m10 = n10; B.m11 = n11;
        }
        // forward operator A_j[n][p] = f_j[n] + T[n][p]
        if (j == lo_f) {
            F.m00 = fx + t00; F.m01 = fx + t01;
            F.m10 = fy + t10; F.m11 = fy + t11;
        } else if (j > lo_f && j <= hi_f) {
            double l0 = lse2d(t00 + F.m00, t01 + F.m10);
            double l1 = lse2d(t00 + F.m01, t01 + F.m11);
            double l2 = lse2d(t10 + F.m00, t11 + F.m10);
            double l3 = lse2d(t10 + F.m01, t11 + F.m11);
            F.m00 = fx + l0; F.m01 = fx + l1;
            F.m10 = fy + l2; F.m11 = fy + l3;
        }
    }
    fwdmat[c] = F;
    bwdmat[c] = B;
}

// ---------------------------------------------------------------------------
// Pass 2: scan over chunk matrices -> per-chunk boundary vectors + Z.
// block 0: forward (startv[c] = alpha_{c*S});  block 1: backward
// (endv[c] = beta_{(c+1)*S-1}).
// ---------------------------------------------------------------------------
__global__ __launch_bounds__(P2_THREADS) void crf_pass2(
    const float* __restrict__ feats,
    const DMat* __restrict__ fwdmat, const DMat* __restrict__ bwdmat,
    double2* __restrict__ startv, double2* __restrict__ endv,
    double* __restrict__ zout)
{
    __shared__ DMat sm[P2_THREADS];
    const int t  = threadIdx.x;
    const int c0 = t * P2_G;

    if (blockIdx.x == 0) {
        DMat M = fwdmat[c0];
        for (int k = 1; k < P2_G; ++k) M = logmm(fwdmat[c0 + k], M);
        sm[t] = M;
        __syncthreads();
        for (int off = 1; off < P2_THREADS; off <<= 1) {
            DMat R; bool act = (t >= off);
            if (act) R = logmm(sm[t], sm[t - off]);
            __syncthreads();
            if (act) sm[t] = R;
            __syncthreads();
        }
        float2 f0 = *(const float2*)feats;
        double v0, v1;
        if (t == 0) { v0 = f0.x; v1 = f0.y; }
        else {
            DMat E = sm[t - 1];
            v0 = lse2d(E.m00 + (double)f0.x, E.m01 + (double)f0.y);
            v1 = lse2d(E.m10 + (double)f0.x, E.m11 + (double)f0.y);
        }
        for (int k = 0; k < P2_G; ++k) {
            int c = c0 + k;
            startv[c] = make_double2(v0, v1);
            DMat P = fwdmat[c];
            double n0 = lse2d(P.m00 + v0, P.m01 + v1);
            double n1 = lse2d(P.m10 + v0, P.m11 + v1);
            v0 = n0; v1 = n1;
        }
        if (t == P2_THREADS - 1) zout[0] = lse2d(v0, v1);  // Z = LSE(alpha_{N-1})
    } else {
        DMat M = bwdmat[c0];
        for (int k = 1; k < P2_G; ++k) M = logmm(M, bwdmat[c0 + k]);
        sm[t] = M;
        __syncthreads();
        for (int off = 1; off < P2_THREADS; off <<= 1) {
            DMat R; bool act = (t + off < P2_THREADS);
            if (act) R = logmm(sm[t], sm[t + off]);
            __syncthreads();
            if (act) sm[t] = R;
            __syncthreads();
        }
        float2 fl = *(const float2*)(feats + 2 * (N_LEN - 1));
        double w0, w1;
        if (t == P2_THREADS - 1) { w0 = fl.x; w1 = fl.y; }
        else {
            DMat Fm = sm[t + 1];
            w0 = lse2d(Fm.m00 + (double)fl.x, Fm.m01 + (double)fl.y);
            w1 = lse2d(Fm.m10 + (double)fl.x, Fm.m11 + (double)fl.y);
        }
        for (int k = P2_G - 1; k >= 0; --k) {
            int c = c0 + k;
            endv[c] = make_double2(w0, w1);
            DMat Q = bwdmat[c];
            double n0 = lse2d(Q.m00 + w0, Q.m01 + w1);
            double n1 = lse2d(Q.m10 + w0, Q.m11 + w1);
            w0 = n0; w1 = n1;
        }
    }
}

// ---------------------------------------------------------------------------
// Pass 3: per chunk, recompute beta backward into REGISTERS (float2 relative
// to a per-chunk double base; fully unrolled so b[] stays in VGPRs), then
// alpha forward + combine: marginal = exp(alpha + beta - f - Z).
// __launch_bounds__(256,1): grid is exactly 256 blocks (1 block/CU, 1
// wave/SIMD) so there is no occupancy to protect — let VGPRs go to ~512.
// ---------------------------------------------------------------------------
__global__ __launch_bounds__(P1_BLOCK, 1) void crf_pass3(
    const float* __restrict__ feats, const float* __restrict__ trans,
    const double2* __restrict__ startv, const double2* __restrict__ endv,
    const double* __restrict__ zptr, float* __restrict__ out)
{
    const int c = blockIdx.x * blockDim.x + threadIdx.x;
    const double t00 = trans[0], t01 = trans[1], t10 = trans[2], t11 = trans[3];
    const double Z = zptr[0];
    const int lo = c * S_CHUNK;
    float2* outv = (float2*)out;

    // phase A: beta backward, registers, relative to base
    float2 b[S_CHUNK];
    double2 w = endv[c];
    const double base = w.x;
    b[S_CHUNK - 1] = make_float2((float)(w.x - base), (float)(w.y - base));
    #pragma unroll
    for (int k = S_CHUNK - 2; k >= 0; --k) {
        float2 fi = *(const float2*)(feats + 2 * (lo + k));
        double n0 = fi.x + lse2d(t00 + w.x, t10 + w.y);  // beta[0]
        double n1 = fi.y + lse2d(t01 + w.x, t11 + w.y);  // beta[1]
        w.x = n0; w.y = n1;
        b[k] = make_float2((float)(w.x - base), (float)(w.y - base));
    }

    // phase B: alpha forward + combine
    double2 v = startv[c];
    const double zb = Z - base;
    #pragma unroll
    for (int k = 0; k < S_CHUNK; ++k) {
        float2 fi = *(const float2*)(feats + 2 * (lo + k));
        if (k > 0) {
            double n0 = fi.x + lse2d(t00 + v.x, t01 + v.y);
            double n1 = fi.y + lse2d(t10 + v.x, t11 + v.y);
            v.x = n0; v.y = n1;
        }
        float m0 = (float)((v.x - zb) + (double)(b[k].x - fi.x));
        float m1 = (float)((v.y - zb) + (double)(b[k].y - fi.y));
        outv[lo + k] = make_float2(__expf(m0), __expf(m1));
    }
}

extern "C" void kernel_launch(void* const* d_in, const int* in_sizes, int n_in,
                              void* d_out, int out_size, void* d_ws, size_t ws_size,
                              hipStream_t stream)
{
    const float* feats = (const float*)d_in[0];
    const float* trans = (const float*)d_in[1];
    float* out = (float*)d_out;

    char* ws = (char*)d_ws;
    DMat*    fwdmat = (DMat*)ws;                                         // 2 MB
    DMat*    bwdmat = (DMat*)(ws + (size_t)N_CHUNKS * sizeof(DMat));     // 2 MB
    double2* startv = (double2*)(ws + (size_t)N_CHUNKS * sizeof(DMat) * 2);          // 1 MB
    double2* endv   = (double2*)(ws + (size_t)N_CHUNKS * (sizeof(DMat) * 2 + 16));   // 1 MB
    double*  zout   = (double*) (ws + (size_t)N_CHUNKS * (sizeof(DMat) * 2 + 32));   // 8 B

    hipLaunchKernelGGL(crf_pass1, dim3(N_CHUNKS / P1_BLOCK), dim3(P1_BLOCK), 0, stream,
                       feats, trans, fwdmat, bwdmat);
    hipLaunchKernelGGL(crf_pass2, dim3(2), dim3(P2_THREADS), 0, stream,
                       feats, fwdmat, bwdmat, startv, endv, zout);
    hipLaunchKernelGGL(crf_pass3, dim3(N_CHUNKS / P1_BLOCK), dim3(P1_BLOCK), 0, stream,
                       feats, trans, startv, endv, zout, out);
}

// Round 9
// 232.716 us; speedup vs baseline: 1.4068x; 1.4068x over previous
//
#include <hip/hip_runtime.h>

// Linear-chain CRF marginals, L = 4M, 2 labels.
// Hierarchical log-semiring scan:
//  K1: per-chunk (64 pos) compose F,B in registers + in-wave Kogge-Stone scan
//      over the 64 chunks of each wave-group -> per-chunk prefix/suffix mats
//      (PF/SB) + per-group mats (GF/GB).  Chunk matrices never hit memory.
//  K2: 1024 group matrices scanned by one block each direction (10 rounds,
//      no serial phases) -> group boundary vectors gstart/gend + Z.
//  K3: per chunk: boundary vectors from PF/SB (x) group vectors; beta walk
//      staged through d_out (no big register array -> no spill risk); alpha
//      walk + combine exp(alpha+beta-f-Z).
// Carries in double, transcendentals in fp32 (LSE correction is O(1)).

#define N_LEN      4194304
#define S_CHUNK    64
#define N_CHUNKS   (N_LEN / S_CHUNK)        // 65536
#define N_GROUPS   (N_CHUNKS / 64)          // 1024
#define P1_BLOCK   256
#define P2_THREADS 1024

__device__ __forceinline__ double lse2d(double x, double y) {
    double mx = fmax(x, y);
    double d  = fmin(x, y) - mx;            // <= 0, O(1) magnitude
    float  cc = __logf(1.0f + __expf((float)d));
    return mx + (double)cc;
}

struct DMat { double m00, m01, m10, m11; }; // M[i][j], row i, col j

__device__ __forceinline__ DMat logmm(const DMat X, const DMat Y) {
    // (X (x) Y)[i][j] = LSE_p(X[i][p] + Y[p][j])  (X applied later)
    DMat R;
    R.m00 = lse2d(X.m00 + Y.m00, X.m01 + Y.m10);
    R.m01 = lse2d(X.m00 + Y.m01, X.m01 + Y.m11);
    R.m10 = lse2d(X.m10 + Y.m00, X.m11 + Y.m10);
    R.m11 = lse2d(X.m10 + Y.m01, X.m11 + Y.m11);
    return R;
}

__device__ __forceinline__ DMat shfl_up_mat(const DMat M, int off) {
    DMat R;
    R.m00 = __shfl_up(M.m00, off, 64);
    R.m01 = __shfl_up(M.m01, off, 64);
    R.m10 = __shfl_up(M.m10, off, 64);
    R.m11 = __shfl_up(M.m11, off, 64);
    return R;
}

__device__ __forceinline__ DMat shfl_down_mat(const DMat M, int off) {
    DMat R;
    R.m00 = __shfl_down(M.m00, off, 64);
    R.m01 = __shfl_down(M.m01, off, 64);
    R.m10 = __shfl_down(M.m10, off, 64);
    R.m11 = __shfl_down(M.m11, off, 64);
    return R;
}

// ---------------------------------------------------------------------------
// K1: chunk compose + in-wave group scan.
// fwd chunk op: F_c = A_hi (x)...(x) A_lo, lo=c*S+1, hi=min((c+1)S, N-1);
//   maps alpha_{c*S} -> alpha at next chunk boundary.
// bwd chunk op: B_c = B_lo' (x)...(x) B_hi', lo'=max(cS-1,0), hi'=(c+1)S-2;
//   maps endv[c] -> endv[c-1].
// Wave lane r, group g=c>>6:
//   PF[c] = F_{g64+r} (x)...(x) F_{g64}   (inclusive prefix)
//   SB[c] = B_{g64+r} (x)...(x) B_{g64+63} (inclusive suffix)
//   GF[g] = PF at lane 63, GB[g] = SB at lane 0.
// ---------------------------------------------------------------------------
__global__ __launch_bounds__(P1_BLOCK) void crf_k1(
    const float* __restrict__ feats, const float* __restrict__ trans,
    DMat* __restrict__ PF, DMat* __restrict__ SB,
    DMat* __restrict__ GF, DMat* __restrict__ GB)
{
    const int c    = blockIdx.x * blockDim.x + threadIdx.x;
    const int lane = threadIdx.x & 63;
    const int g    = c >> 6;
    const double t00 = trans[0], t01 = trans[1], t10 = trans[2], t11 = trans[3];

    const int lo_f = c * S_CHUNK + 1;
    const int hi_f = min((c + 1) * S_CHUNK, N_LEN - 1);
    const int lo_b = max(c * S_CHUNK - 1, 0);
    const int hi_b = (c + 1) * S_CHUNK - 2;

    DMat F, B;
    for (int j = lo_b; j <= hi_f; ++j) {
        float2 f = *(const float2*)(feats + 2 * j);
        const double fx = f.x, fy = f.y;
        // backward operator B_j[p][n] = f_j[p] + T[n][p]
        if (j == lo_b) {
            B.m00 = fx + t00; B.m01 = fx + t10;
            B.m10 = fy + t01; B.m11 = fy + t11;
        } else if (j <= hi_b) {
            double b00 = fx + t00, b01 = fx + t10;
            double b10 = fy + t01, b11 = fy + t11;
            double n00 = lse2d(B.m00 + b00, B.m01 + b10);
            double n01 = lse2d(B.m00 + b01, B.m01 + b11);
            double n10 = lse2d(B.m10 + b00, B.m11 + b10);
            double n11 = lse2d(B.m10 + b01, B.m11 + b11);
            B.m00 = n00; B.m01 = n01; B.m10 = n10; B.m11 = n11;
        }
        // forward operator A_j[n][p] = f_j[n] + T[n][p]
        if (j == lo_f) {
            F.m00 = fx + t00; F.m01 = fx + t01;
            F.m10 = fy + t10; F.m11 = fy + t11;
        } else if (j > lo_f && j <= hi_f) {
            double l0 = lse2d(t00 + F.m00, t01 + F.m10);
            double l1 = lse2d(t00 + F.m01, t01 + F.m11);
            double l2 = lse2d(t10 + F.m00, t11 + F.m10);
            double l3 = lse2d(t10 + F.m01, t11 + F.m11);
            F.m00 = fx + l0; F.m01 = fx + l1;
            F.m10 = fy + l2; F.m11 = fy + l3;
        }
    }

    // in-wave inclusive prefix scan (fwd)
    DMat S = F;
    #pragma unroll
    for (int k = 0; k < 6; ++k) {
        int off = 1 << k;
        DMat o = shfl_up_mat(S, off);
        if (lane >= off) S = logmm(S, o);
    }
    PF[c] = S;
    if (lane == 63) GF[g] = S;

    // in-wave inclusive suffix scan (bwd)
    DMat T = B;
    #pragma unroll
    for (int k = 0; k < 6; ++k) {
        int off = 1 << k;
        DMat o = shfl_down_mat(T, off);
        if (lane + off < 64) T = logmm(T, o);
    }
    SB[c] = T;
    if (lane == 0) GB[g] = T;
}

// ---------------------------------------------------------------------------
// K2: scan the 1024 group matrices.
// block 0: prefix over GF -> gstart[g] = alpha at group-g start; Z.
// block 1: suffix over GB -> gend[g] = beta at group-g end.
// ---------------------------------------------------------------------------
__global__ __launch_bounds__(P2_THREADS) void crf_k2(
    const float* __restrict__ feats,
    const DMat* __restrict__ GF, const DMat* __restrict__ GB,
    double2* __restrict__ gstart, double2* __restrict__ gend,
    double* __restrict__ zout)
{
    __shared__ DMat sm[P2_THREADS];
    const int t = threadIdx.x;

    if (blockIdx.x == 0) {
        sm[t] = GF[t];
        __syncthreads();
        for (int off = 1; off < P2_THREADS; off <<= 1) {
            DMat R; bool act = (t >= off);
            if (act) R = logmm(sm[t], sm[t - off]);
            __syncthreads();
            if (act) sm[t] = R;
            __syncthreads();
        }
        float2 f0 = *(const float2*)feats;
        if (t == 0) {
            gstart[0] = make_double2((double)f0.x, (double)f0.y);
        } else {
            DMat E = sm[t - 1];
            gstart[t] = make_double2(
                lse2d(E.m00 + (double)f0.x, E.m01 + (double)f0.y),
                lse2d(E.m10 + (double)f0.x, E.m11 + (double)f0.y));
        }
        if (t == P2_THREADS - 1) {
            DMat E = sm[t];  // maps alpha_0 -> alpha_{N-1}
            double a0 = lse2d(E.m00 + (double)f0.x, E.m01 + (double)f0.y);
            double a1 = lse2d(E.m10 + (double)f0.x, E.m11 + (double)f0.y);
            zout[0] = lse2d(a0, a1);
        }
    } else {
        sm[t] = GB[t];
        __syncthreads();
        for (int off = 1; off < P2_THREADS; off <<= 1) {
            DMat R; bool act = (t + off < P2_THREADS);
            if (act) R = logmm(sm[t], sm[t + off]);
            __syncthreads();
            if (act) sm[t] = R;
            __syncthreads();
        }
        float2 fl = *(const float2*)(feats + 2 * (N_LEN - 1));
        if (t == P2_THREADS - 1) {
            gend[t] = make_double2((double)fl.x, (double)fl.y);
        } else {
            DMat E = sm[t + 1];
            gend[t] = make_double2(
                lse2d(E.m00 + (double)fl.x, E.m01 + (double)fl.y),
                lse2d(E.m10 + (double)fl.x, E.m11 + (double)fl.y));
        }
    }
}

// ---------------------------------------------------------------------------
// K3: per chunk: startv = PF[c-1] (x) gstart[g] (r>0) else gstart[g];
//               endv   = SB[c+1] (x) gend[g]   (r<63) else gend[g].
// beta walk staged into d_out (float2 rel double base), then alpha walk +
// combine: marginal = exp(alpha + beta - f - Z).
// ---------------------------------------------------------------------------
__global__ __launch_bounds__(P1_BLOCK) void crf_k3(
    const float* __restrict__ feats, const float* __restrict__ trans,
    const DMat* __restrict__ PF, const DMat* __restrict__ SB,
    const double2* __restrict__ gstart, const double2* __restrict__ gend,
    const double* __restrict__ zptr, float* __restrict__ out)
{
    const int c = blockIdx.x * blockDim.x + threadIdx.x;
    const int g = c >> 6, r = c & 63;
    const double t00 = trans[0], t01 = trans[1], t10 = trans[2], t11 = trans[3];
    const double Z = zptr[0];
    const int lo = c * S_CHUNK, hi = lo + S_CHUNK - 1;
    float2* outv = (float2*)out;

    double2 gs = gstart[g], ge = gend[g];
    double2 v, w;
    if (r == 0) {
        v = gs;
    } else {
        DMat P = PF[c - 1];
        v = make_double2(lse2d(P.m00 + gs.x, P.m01 + gs.y),
                         lse2d(P.m10 + gs.x, P.m11 + gs.y));
    }
    if (r == 63) {
        w = ge;
    } else {
        DMat Tm = SB[c + 1];
        w = make_double2(lse2d(Tm.m00 + ge.x, Tm.m01 + ge.y),
                         lse2d(Tm.m10 + ge.x, Tm.m11 + ge.y));
    }

    // phase A: beta backward, staged into out relative to base
    const double base = w.x;
    outv[hi] = make_float2(0.0f, (float)(w.y - base));
    for (int i = hi - 1; i >= lo; --i) {
        float2 fi = *(const float2*)(feats + 2 * i);
        double n0 = fi.x + lse2d(t00 + w.x, t10 + w.y);  // beta_i[0]
        double n1 = fi.y + lse2d(t01 + w.x, t11 + w.y);  // beta_i[1]
        w.x = n0; w.y = n1;
        outv[i] = make_float2((float)(w.x - base), (float)(w.y - base));
    }

    // phase B: alpha forward + combine
    const double zb = Z - base;
    for (int i = lo; i <= hi; ++i) {
        float2 fi = *(const float2*)(feats + 2 * i);
        if (i > lo) {
            double n0 = fi.x + lse2d(t00 + v.x, t01 + v.y);
            double n1 = fi.y + lse2d(t10 + v.x, t11 + v.y);
            v.x = n0; v.y = n1;
        }
        float2 br = outv[i];
        float m0 = (float)((v.x - zb) + (double)(br.x - fi.x));
        float m1 = (float)((v.y - zb) + (double)(br.y - fi.y));
        outv[i] = make_float2(__expf(m0), __expf(m1));
    }
}

extern "C" void kernel_launch(void* const* d_in, const int* in_sizes, int n_in,
                              void* d_out, int out_size, void* d_ws, size_t ws_size,
                              hipStream_t stream)
{
    const float* feats = (const float*)d_in[0];
    const float* trans = (const float*)d_in[1];
    float* out = (float*)d_out;

    char* ws = (char*)d_ws;
    size_t off = 0;
    DMat* PF = (DMat*)(ws + off); off += (size_t)N_CHUNKS * sizeof(DMat);   // 2 MB
    DMat* SB = (DMat*)(ws + off); off += (size_t)N_CHUNKS * sizeof(DMat);   // 2 MB
    DMat* GF = (DMat*)(ws + off); off += (size_t)N_GROUPS * sizeof(DMat);   // 32 KB
    DMat* GB = (DMat*)(ws + off); off += (size_t)N_GROUPS * sizeof(DMat);   // 32 KB
    double2* gstart = (double2*)(ws + off); off += (size_t)N_GROUPS * sizeof(double2);
    double2* gend   = (double2*)(ws + off); off += (size_t)N_GROUPS * sizeof(double2);
    double*  zout   = (double*)(ws + off);

    hipLaunchKernelGGL(crf_k1, dim3(N_CHUNKS / P1_BLOCK), dim3(P1_BLOCK), 0, stream,
                       feats, trans, PF, SB, GF, GB);
    hipLaunchKernelGGL(crf_k2, dim3(2), dim3(P2_THREADS), 0, stream,
                       feats, GF, GB, gstart, gend, zout);
    hipLaunchKernelGGL(crf_k3, dim3(N_CHUNKS / P1_BLOCK), dim3(P1_BLOCK), 0, stream,
                       feats, trans, PF, SB, gstart, gend, zout, out);
}

// Round 10
// 156.366 us; speedup vs baseline: 2.0937x; 1.4883x over previous
//
#include <hip/hip_runtime.h>

// Linear-chain CRF marginals, L = 4M, 2 labels.
// Hierarchical log-semiring scan, S_CHUNK=16:
//  K1: per-chunk (16 pos) compose F,B in registers + in-wave Kogge-Stone scan
//      over 64 chunks/wave-group -> PF/SB (per-chunk prefix/suffix mats) +
//      GF/GB (4096 group mats).  1024 blocks -> 4 blocks/CU.
//  K2: 4096 group matrices: 1024 threads serial-compose 4 + Hillis-Steele
//      10 rounds -> group boundary vectors gstart/gend + Z.
//  K3: per chunk: boundary vectors from PF/SB (x) group vectors; beta in
//      16 float2 REGISTERS (base-relative); feats staged coalesced into a
//      bank-padded LDS tile; marginals written back through the same tile
//      fully coalesced (kills the 9x partial-line write amplification seen
//      at S=64: WRITE_SIZE 537 MB for 64 MB of logical writes).
// Carries in double, transcendentals in fp32 (LSE correction is O(1)).

#define N_LEN    4194304
#define SC       16
#define NC       (N_LEN / SC)       // 262144 chunks
#define NG       (NC / 64)          // 4096 groups (64 chunks per wave-group)
#define K1_BLOCK 256
#define K2_T     1024
#define K2_G     (NG / K2_T)        // 4
#define K3_CPB   256                // chunks per block (= threads)
#define K3_TILE  (K3_CPB * SC)      // 4096 positions per block
#define LROW     33                 // LDS floats per chunk row (32 + 1 pad)

__device__ __forceinline__ double lse2d(double x, double y) {
    double mx = fmax(x, y);
    double d  = fmin(x, y) - mx;            // <= 0, O(1) magnitude
    float  cc = __logf(1.0f + __expf((float)d));
    return mx + (double)cc;
}

struct DMat { double m00, m01, m10, m11; }; // M[i][j]

__device__ __forceinline__ DMat logmm(const DMat X, const DMat Y) {
    // (X (x) Y) applied to v = X(Y(v))
    DMat R;
    R.m00 = lse2d(X.m00 + Y.m00, X.m01 + Y.m10);
    R.m01 = lse2d(X.m00 + Y.m01, X.m01 + Y.m11);
    R.m10 = lse2d(X.m10 + Y.m00, X.m11 + Y.m10);
    R.m11 = lse2d(X.m10 + Y.m01, X.m11 + Y.m11);
    return R;
}

__device__ __forceinline__ DMat shfl_up_mat(const DMat M, int off) {
    DMat R;
    R.m00 = __shfl_up(M.m00, off, 64);
    R.m01 = __shfl_up(M.m01, off, 64);
    R.m10 = __shfl_up(M.m10, off, 64);
    R.m11 = __shfl_up(M.m11, off, 64);
    return R;
}

__device__ __forceinline__ DMat shfl_down_mat(const DMat M, int off) {
    DMat R;
    R.m00 = __shfl_down(M.m00, off, 64);
    R.m01 = __shfl_down(M.m01, off, 64);
    R.m10 = __shfl_down(M.m10, off, 64);
    R.m11 = __shfl_down(M.m11, off, 64);
    return R;
}

// ---------------------------------------------------------------------------
// K1: chunk compose + in-wave group scan (identical algebra to the verified
// S=64 version, only SC changed).
// ---------------------------------------------------------------------------
__global__ __launch_bounds__(K1_BLOCK, 4) void crf_k1(
    const float* __restrict__ feats, const float* __restrict__ trans,
    DMat* __restrict__ PF, DMat* __restrict__ SB,
    DMat* __restrict__ GF, DMat* __restrict__ GB)
{
    const int c    = blockIdx.x * blockDim.x + threadIdx.x;
    const int lane = threadIdx.x & 63;
    const int g    = c >> 6;
    const double t00 = trans[0], t01 = trans[1], t10 = trans[2], t11 = trans[3];

    const int lo_f = c * SC + 1;
    const int hi_f = min((c + 1) * SC, N_LEN - 1);
    const int lo_b = max(c * SC - 1, 0);
    const int hi_b = (c + 1) * SC - 2;

    DMat F, B;
    for (int j = lo_b; j <= hi_f; ++j) {
        float2 f = *(const float2*)(feats + 2 * j);
        const double fx = f.x, fy = f.y;
        // backward operator B_j[p][n] = f_j[p] + T[n][p]
        if (j == lo_b) {
            B.m00 = fx + t00; B.m01 = fx + t10;
            B.m10 = fy + t01; B.m11 = fy + t11;
        } else if (j <= hi_b) {
            double b00 = fx + t00, b01 = fx + t10;
            double b10 = fy + t01, b11 = fy + t11;
            double n00 = lse2d(B.m00 + b00, B.m01 + b10);
            double n01 = lse2d(B.m00 + b01, B.m01 + b11);
            double n10 = lse2d(B.m10 + b00, B.m11 + b10);
            double n11 = lse2d(B.m10 + b01, B.m11 + b11);
            B.m00 = n00; B.m01 = n01; B.m10 = n10; B.m11 = n11;
        }
        // forward operator A_j[n][p] = f_j[n] + T[n][p]
        if (j == lo_f) {
            F.m00 = fx + t00; F.m01 = fx + t01;
            F.m10 = fy + t10; F.m11 = fy + t11;
        } else if (j > lo_f && j <= hi_f) {
            double l0 = lse2d(t00 + F.m00, t01 + F.m10);
            double l1 = lse2d(t00 + F.m01, t01 + F.m11);
            double l2 = lse2d(t10 + F.m00, t11 + F.m10);
            double l3 = lse2d(t10 + F.m01, t11 + F.m11);
            F.m00 = fx + l0; F.m01 = fx + l1;
            F.m10 = fy + l2; F.m11 = fy + l3;
        }
    }

    // in-wave inclusive prefix scan (fwd)
    DMat S = F;
    #pragma unroll
    for (int k = 0; k < 6; ++k) {
        int off = 1 << k;
        DMat o = shfl_up_mat(S, off);
        if (lane >= off) S = logmm(S, o);
    }
    PF[c] = S;
    if (lane == 63) GF[g] = S;

    // in-wave inclusive suffix scan (bwd)
    DMat T = B;
    #pragma unroll
    for (int k = 0; k < 6; ++k) {
        int off = 1 << k;
        DMat o = shfl_down_mat(T, off);
        if (lane + off < 64) T = logmm(T, o);
    }
    SB[c] = T;
    if (lane == 0) GB[g] = T;
}

// ---------------------------------------------------------------------------
// K2: 4096 group matrices -> gstart/gend + Z.  Thread t owns groups
// 4t..4t+3: serial compose (registers), Hillis-Steele over 1024, serial walk.
// ---------------------------------------------------------------------------
__global__ __launch_bounds__(K2_T) void crf_k2(
    const float* __restrict__ feats,
    const DMat* __restrict__ GF, const DMat* __restrict__ GB,
    double2* __restrict__ gstart, double2* __restrict__ gend,
    double* __restrict__ zout)
{
    __shared__ DMat sm[K2_T];
    const int t  = threadIdx.x;
    const int c0 = t * K2_G;

    if (blockIdx.x == 0) {
        DMat M = GF[c0];
        #pragma unroll
        for (int k = 1; k < K2_G; ++k) M = logmm(GF[c0 + k], M);
        sm[t] = M;
        __syncthreads();
        for (int off = 1; off < K2_T; off <<= 1) {
            DMat R; bool act = (t >= off);
            if (act) R = logmm(sm[t], sm[t - off]);
            __syncthreads();
            if (act) sm[t] = R;
            __syncthreads();
        }
        float2 f0 = *(const float2*)feats;
        double v0, v1;
        if (t == 0) { v0 = f0.x; v1 = f0.y; }
        else {
            DMat E = sm[t - 1];
            v0 = lse2d(E.m00 + (double)f0.x, E.m01 + (double)f0.y);
            v1 = lse2d(E.m10 + (double)f0.x, E.m11 + (double)f0.y);
        }
        #pragma unroll
        for (int k = 0; k < K2_G; ++k) {
            int c = c0 + k;
            gstart[c] = make_double2(v0, v1);
            DMat P = GF[c];
            double n0 = lse2d(P.m00 + v0, P.m01 + v1);
            double n1 = lse2d(P.m10 + v0, P.m11 + v1);
            v0 = n0; v1 = n1;
        }
        if (t == K2_T - 1) zout[0] = lse2d(v0, v1);  // Z = LSE(alpha_{N-1})
    } else {
        DMat M = GB[c0];
        #pragma unroll
        for (int k = 1; k < K2_G; ++k) M = logmm(M, GB[c0 + k]);
        sm[t] = M;
        __syncthreads();
        for (int off = 1; off < K2_T; off <<= 1) {
            DMat R; bool act = (t + off < K2_T);
            if (act) R = logmm(sm[t], sm[t + off]);
            __syncthreads();
            if (act) sm[t] = R;
            __syncthreads();
        }
        float2 fl = *(const float2*)(feats + 2 * (N_LEN - 1));
        double w0, w1;
        if (t == K2_T - 1) { w0 = fl.x; w1 = fl.y; }
        else {
            DMat E = sm[t + 1];
            w0 = lse2d(E.m00 + (double)fl.x, E.m01 + (double)fl.y);
            w1 = lse2d(E.m10 + (double)fl.x, E.m11 + (double)fl.y);
        }
        #pragma unroll
        for (int k = K2_G - 1; k >= 0; --k) {
            int c = c0 + k;
            gend[c] = make_double2(w0, w1);
            DMat Q = GB[c];
            double n0 = lse2d(Q.m00 + w0, Q.m01 + w1);
            double n1 = lse2d(Q.m10 + w0, Q.m11 + w1);
            w0 = n0; w1 = n1;
        }
    }
}

// ---------------------------------------------------------------------------
// K3: block = 256 threads = 256 chunks = 4096 positions.
//  P0: coalesced load feats tile -> padded LDS (stride LROW floats/chunk).
//  PA: beta backward into 16 float2 regs (base-relative), feats from LDS.
//  PB: alpha forward + combine; marginal written into the SAME LDS slots.
//  PC: coalesced store LDS tile -> out.
// ---------------------------------------------------------------------------
__global__ __launch_bounds__(K3_CPB, 4) void crf_k3(
    const float* __restrict__ feats, const float* __restrict__ trans,
    const DMat* __restrict__ PF, const DMat* __restrict__ SB,
    const double2* __restrict__ gstart, const double2* __restrict__ gend,
    const double* __restrict__ zptr, float* __restrict__ out)
{
    __shared__ float lds[K3_CPB * LROW];   // 33 KB
    const int t = threadIdx.x;
    const int c = blockIdx.x * K3_CPB + t;
    const int g = c >> 6, r = c & 63;
    const int tile = blockIdx.x * K3_TILE; // position base of this block
    const double t00 = trans[0], t01 = trans[1], t10 = trans[2], t11 = trans[3];
    const double Z = zptr[0];
    const float2* fv = (const float2*)feats;

    // P0: coalesced feats -> LDS (pos p -> lds[(p/SC)*LROW + 2*(p%SC)])
    #pragma unroll
    for (int k = 0; k < SC; ++k) {
        int p = k * K3_CPB + t;
        float2 f = fv[tile + p];
        int cc = p >> 4, ii = p & 15;
        lds[cc * LROW + 2 * ii]     = f.x;
        lds[cc * LROW + 2 * ii + 1] = f.y;
    }

    // boundary vectors (global, coalesced 64B/lane)
    double2 gs = gstart[g], ge = gend[g];
    double2 v, w;
    if (r == 0) {
        v = gs;
    } else {
        DMat P = PF[c - 1];
        v = make_double2(lse2d(P.m00 + gs.x, P.m01 + gs.y),
                         lse2d(P.m10 + gs.x, P.m11 + gs.y));
    }
    if (r == 63) {
        w = ge;
    } else {
        DMat Tm = SB[c + 1];
        w = make_double2(lse2d(Tm.m00 + ge.x, Tm.m01 + ge.y),
                         lse2d(Tm.m10 + ge.x, Tm.m11 + ge.y));
    }
    __syncthreads();

    const float* myrow = lds + t * LROW;
    float* myroww = lds + t * LROW;

    // PA: beta backward into registers, relative to base
    float bx[SC], by[SC];
    const double base = w.x;
    bx[SC - 1] = 0.0f;
    by[SC - 1] = (float)(w.y - base);
    #pragma unroll
    for (int k = SC - 2; k >= 0; --k) {
        double fx = (double)myrow[2 * k], fy = (double)myrow[2 * k + 1];
        double n0 = fx + lse2d(t00 + w.x, t10 + w.y);  // beta[0]
        double n1 = fy + lse2d(t01 + w.x, t11 + w.y);  // beta[1]
        w.x = n0; w.y = n1;
        bx[k] = (float)(w.x - base);
        by[k] = (float)(w.y - base);
    }

    // PB: alpha forward + combine, write marginal into same LDS slots
    const double zb = Z - base;
    #pragma unroll
    for (int k = 0; k < SC; ++k) {
        float fxf = myrow[2 * k], fyf = myrow[2 * k + 1];
        if (k > 0) {
            double n0 = (double)fxf + lse2d(t00 + v.x, t01 + v.y);
            double n1 = (double)fyf + lse2d(t10 + v.x, t11 + v.y);
            v.x = n0; v.y = n1;
        }
        float m0 = (float)((v.x - zb) + (double)(bx[k] - fxf));
        float m1 = (float)((v.y - zb) + (double)(by[k] - fyf));
        myroww[2 * k]     = __expf(m0);
        myroww[2 * k + 1] = __expf(m1);
    }
    __syncthreads();

    // PC: coalesced store LDS -> out
    float2* ov = (float2*)out;
    #pragma unroll
    for (int k = 0; k < SC; ++k) {
        int p = k * K3_CPB + t;
        int cc = p >> 4, ii = p & 15;
        ov[tile + p] = make_float2(lds[cc * LROW + 2 * ii],
                                   lds[cc * LROW + 2 * ii + 1]);
    }
}

extern "C" void kernel_launch(void* const* d_in, const int* in_sizes, int n_in,
                              void* d_out, int out_size, void* d_ws, size_t ws_size,
                              hipStream_t stream)
{
    const float* feats = (const float*)d_in[0];
    const float* trans = (const float*)d_in[1];
    float* out = (float*)d_out;

    char* ws = (char*)d_ws;
    size_t off = 0;
    DMat* PF = (DMat*)(ws + off); off += (size_t)NC * sizeof(DMat);   // 16 MB
    DMat* SB = (DMat*)(ws + off); off += (size_t)NC * sizeof(DMat);   // 16 MB
    DMat* GF = (DMat*)(ws + off); off += (size_t)NG * sizeof(DMat);   // 256 KB
    DMat* GB = (DMat*)(ws + off); off += (size_t)NG * sizeof(DMat);   // 256 KB
    double2* gstart = (double2*)(ws + off); off += (size_t)NG * sizeof(double2);
    double2* gend   = (double2*)(ws + off); off += (size_t)NG * sizeof(double2);
    double*  zout   = (double*)(ws + off);

    hipLaunchKernelGGL(crf_k1, dim3(NC / K1_BLOCK), dim3(K1_BLOCK), 0, stream,
                       feats, trans, PF, SB, GF, GB);
    hipLaunchKernelGGL(crf_k2, dim3(2), dim3(K2_T), 0, stream,
                       feats, GF, GB, gstart, gend, zout);
    hipLaunchKernelGGL(crf_k3, dim3(NC / K3_CPB), dim3(K3_CPB), 0, stream,
                       feats, trans, PF, SB, gstart, gend, zout, out);
}

// Round 11
// 137.716 us; speedup vs baseline: 2.3773x; 1.1354x over previous
//
#include <hip/hip_runtime.h>

// Linear-chain CRF marginals, L = 4M, 2 labels.
// Hierarchical log-semiring scan, SC=16, group = 256 chunks (= 1 block):
//  K1: per-chunk compose F,B in FP32 registers (chunk-local magnitudes O(40))
//      -> f64 in-wave Kogge-Stone over 64 chunks -> cross-wave LDS combine
//      (4 waves/block) -> PF/SB per-chunk prefix/suffix (stored f32) +
//      GF/GB per-group mats (f64, 1024 groups).
//  K2: 1024 group mats, 1024 threads, pure 10-round Hillis-Steele (no serial
//      phases) -> gstart/gend + Z.  LDS as 4 double arrays.
//  K3: boundary vectors from f32 PF/SB (x) group vectors (f64, one-shot);
//      beta+alpha walks in FP32 relative to f64 chunk bases; feats staged
//      through padded LDS tile; fully coalesced in/out.
// Precision: abs err ~2e-6 (compose) + ~5e-4 (PF/SB f32 quant, one-shot)
// + ~2e-5 (walks) in log domain -> marginal rel err < ~1e-3.

#define N_LEN    4194304
#define SC       16
#define NC       (N_LEN / SC)       // 262144 chunks
#define CPB      256                // chunks per block = group size
#define NG       (NC / CPB)         // 1024 groups
#define K2_T     1024
#define LROW     33                 // LDS floats per chunk row (32 + 1 pad)

__device__ __forceinline__ float lse2f(float x, float y) {
    float mx = fmaxf(x, y);
    float d  = fminf(x, y) - mx;
    return mx + __logf(1.0f + __expf(d));
}

__device__ __forceinline__ double lse2d(double x, double y) {
    double mx = fmax(x, y);
    double d  = fmin(x, y) - mx;
    float  cc = __logf(1.0f + __expf((float)d));
    return mx + (double)cc;
}

struct DMat { double m00, m01, m10, m11; };
struct FMat { float  m00, m01, m10, m11; };

__device__ __forceinline__ DMat logmm(const DMat X, const DMat Y) {
    // (X (x) Y)[i][j] = LSE_p(X[i][p] + Y[p][j])  (X applied later)
    DMat R;
    R.m00 = lse2d(X.m00 + Y.m00, X.m01 + Y.m10);
    R.m01 = lse2d(X.m00 + Y.m01, X.m01 + Y.m11);
    R.m10 = lse2d(X.m10 + Y.m00, X.m11 + Y.m10);
    R.m11 = lse2d(X.m10 + Y.m01, X.m11 + Y.m11);
    return R;
}

__device__ __forceinline__ DMat shfl_up_mat(const DMat M, int off) {
    DMat R;
    R.m00 = __shfl_up(M.m00, off, 64);
    R.m01 = __shfl_up(M.m01, off, 64);
    R.m10 = __shfl_up(M.m10, off, 64);
    R.m11 = __shfl_up(M.m11, off, 64);
    return R;
}

__device__ __forceinline__ DMat shfl_down_mat(const DMat M, int off) {
    DMat R;
    R.m00 = __shfl_down(M.m00, off, 64);
    R.m01 = __shfl_down(M.m01, off, 64);
    R.m10 = __shfl_down(M.m10, off, 64);
    R.m11 = __shfl_down(M.m11, off, 64);
    return R;
}

// ---------------------------------------------------------------------------
// K1: fp32 chunk compose + f64 in-wave scan + cross-wave combine.
// Block = 256 threads = 256 chunks = 1 group (4096 positions).
// PF[c] = F_c (x)...(x) F_{group start}   (inclusive prefix, f32 store)
// SB[c] = B_c (x)...(x) B_{group end}     (inclusive suffix, f32 store)
// GF[g]/GB[g]: full group products (f64).
// ---------------------------------------------------------------------------
__global__ __launch_bounds__(CPB, 4) void crf_k1(
    const float* __restrict__ feats, const float* __restrict__ trans,
    FMat* __restrict__ PF, FMat* __restrict__ SB,
    DMat* __restrict__ GF, DMat* __restrict__ GB)
{
    const int c    = blockIdx.x * blockDim.x + threadIdx.x;
    const int lane = threadIdx.x & 63;
    const int wv   = threadIdx.x >> 6;        // wave 0..3
    const float t00 = trans[0], t01 = trans[1], t10 = trans[2], t11 = trans[3];

    const int lo_f = c * SC + 1;
    const int hi_f = min((c + 1) * SC, N_LEN - 1);
    const int lo_b = max(c * SC - 1, 0);
    const int hi_b = (c + 1) * SC - 2;

    // fp32 chunk compose (magnitudes chunk-local, O(40))
    FMat F, B;
    for (int j = lo_b; j <= hi_f; ++j) {
        float2 f = *(const float2*)(feats + 2 * j);
        const float fx = f.x, fy = f.y;
        // backward operator B_j[p][n] = f_j[p] + T[n][p]
        if (j == lo_b) {
            B.m00 = fx + t00; B.m01 = fx + t10;
            B.m10 = fy + t01; B.m11 = fy + t11;
        } else if (j <= hi_b) {
            float b00 = fx + t00, b01 = fx + t10;
            float b10 = fy + t01, b11 = fy + t11;
            float n00 = lse2f(B.m00 + b00, B.m01 + b10);
            float n01 = lse2f(B.m00 + b01, B.m01 + b11);
            float n10 = lse2f(B.m10 + b00, B.m11 + b10);
            float n11 = lse2f(B.m10 + b01, B.m11 + b11);
            B.m00 = n00; B.m01 = n01; B.m10 = n10; B.m11 = n11;
        }
        // forward operator A_j[n][p] = f_j[n] + T[n][p]
        if (j == lo_f) {
            F.m00 = fx + t00; F.m01 = fx + t01;
            F.m10 = fy + t10; F.m11 = fy + t11;
        } else if (j > lo_f && j <= hi_f) {
            float l0 = lse2f(t00 + F.m00, t01 + F.m10);
            float l1 = lse2f(t00 + F.m01, t01 + F.m11);
            float l2 = lse2f(t10 + F.m00, t11 + F.m10);
            float l3 = lse2f(t10 + F.m01, t11 + F.m11);
            F.m00 = fx + l0; F.m01 = fx + l1;
            F.m10 = fy + l2; F.m11 = fy + l3;
        }
    }

    // promote to f64 for the scans
    DMat S = { (double)F.m00, (double)F.m01, (double)F.m10, (double)F.m11 };
    DMat T = { (double)B.m00, (double)B.m01, (double)B.m10, (double)B.m11 };

    // in-wave inclusive prefix scan (fwd)
    #pragma unroll
    for (int k = 0; k < 6; ++k) {
        int off = 1 << k;
        DMat o = shfl_up_mat(S, off);
        if (lane >= off) S = logmm(S, o);
    }
    // in-wave inclusive suffix scan (bwd)
    #pragma unroll
    for (int k = 0; k < 6; ++k) {
        int off = 1 << k;
        DMat o = shfl_down_mat(T, off);
        if (lane + off < 64) T = logmm(T, o);
    }

    // cross-wave combine via LDS (wave products)
    __shared__ DMat wp[4], sb[4];
    if (lane == 63) wp[wv] = S;
    if (lane == 0)  sb[wv] = T;
    __syncthreads();
    if (wv > 0) {
        DMat Pre = wp[0];
        for (int u = 1; u < wv; ++u) Pre = logmm(wp[u], Pre);
        S = logmm(S, Pre);
    }
    if (wv < 3) {
        DMat Suf = sb[3];
        for (int u = 2; u > wv; --u) Suf = logmm(sb[u], Suf);
        T = logmm(T, Suf);
    }

    PF[c] = { (float)S.m00, (float)S.m01, (float)S.m10, (float)S.m11 };
    SB[c] = { (float)T.m00, (float)T.m01, (float)T.m10, (float)T.m11 };
    if (wv == 3 && lane == 63) GF[blockIdx.x] = S;
    if (wv == 0 && lane == 0)  GB[blockIdx.x] = T;
}

// ---------------------------------------------------------------------------
// K2: 1024 group matrices -> gstart/gend + Z.  Pure Hillis-Steele (10
// rounds), no serial phases.  block 0 = fwd, block 1 = bwd.
// ---------------------------------------------------------------------------
__global__ __launch_bounds__(K2_T) void crf_k2(
    const float* __restrict__ feats,
    const DMat* __restrict__ GF, const DMat* __restrict__ GB,
    double2* __restrict__ gstart, double2* __restrict__ gend,
    double* __restrict__ zout)
{
    __shared__ double s00[K2_T], s01[K2_T], s10[K2_T], s11[K2_T];
    const int t = threadIdx.x;

    if (blockIdx.x == 0) {
        DMat M = GF[t];
        s00[t] = M.m00; s01[t] = M.m01; s10[t] = M.m10; s11[t] = M.m11;
        __syncthreads();
        for (int off = 1; off < K2_T; off <<= 1) {
            if (t >= off) {
                DMat O = { s00[t-off], s01[t-off], s10[t-off], s11[t-off] };
                M = logmm(M, O);
            }
            __syncthreads();
            s00[t] = M.m00; s01[t] = M.m01; s10[t] = M.m10; s11[t] = M.m11;
            __syncthreads();
        }
        float2 f0 = *(const float2*)feats;
        if (t == 0) {
            gstart[0] = make_double2((double)f0.x, (double)f0.y);
        } else {
            DMat E = { s00[t-1], s01[t-1], s10[t-1], s11[t-1] };
            gstart[t] = make_double2(
                lse2d(E.m00 + (double)f0.x, E.m01 + (double)f0.y),
                lse2d(E.m10 + (double)f0.x, E.m11 + (double)f0.y));
        }
        if (t == K2_T - 1) {
            double a0 = lse2d(M.m00 + (double)f0.x, M.m01 + (double)f0.y);
            double a1 = lse2d(M.m10 + (double)f0.x, M.m11 + (double)f0.y);
            zout[0] = lse2d(a0, a1);   // Z = LSE(alpha_{N-1})
        }
    } else {
        DMat M = GB[t];
        s00[t] = M.m00; s01[t] = M.m01; s10[t] = M.m10; s11[t] = M.m11;
        __syncthreads();
        for (int off = 1; off < K2_T; off <<= 1) {
            if (t + off < K2_T) {
                DMat O = { s00[t+off], s01[t+off], s10[t+off], s11[t+off] };
                M = logmm(M, O);
            }
            __syncthreads();
            s00[t] = M.m00; s01[t] = M.m01; s10[t] = M.m10; s11[t] = M.m11;
            __syncthreads();
        }
        float2 fl = *(const float2*)(feats + 2 * (N_LEN - 1));
        if (t == K2_T - 1) {
            gend[t] = make_double2((double)fl.x, (double)fl.y);
        } else {
            DMat E = { s00[t+1], s01[t+1], s10[t+1], s11[t+1] };
            gend[t] = make_double2(
                lse2d(E.m00 + (double)fl.x, E.m01 + (double)fl.y),
                lse2d(E.m10 + (double)fl.x, E.m11 + (double)fl.y));
        }
    }
}

// ---------------------------------------------------------------------------
// K3: block = 256 threads = 256 chunks = 1 group (4096 positions).
//  P0: coalesced feats -> padded LDS.
//  boundary: v/w from f32 PF/SB (x) f64 group vectors (one-shot f64 math).
//  PA: beta walk fp32 relative to f64 base (registers).
//  PB: alpha walk fp32 relative + combine; marginals into same LDS slots.
//  PC: coalesced store -> out.
// ---------------------------------------------------------------------------
__global__ __launch_bounds__(CPB, 4) void crf_k3(
    const float* __restrict__ feats, const float* __restrict__ trans,
    const FMat* __restrict__ PF, const FMat* __restrict__ SB,
    const double2* __restrict__ gstart, const double2* __restrict__ gend,
    const double* __restrict__ zptr, float* __restrict__ out)
{
    __shared__ float lds[CPB * LROW];   // 33 KB
    const int t = threadIdx.x;
    const int c = blockIdx.x * CPB + t;
    const int g = c >> 8, r = c & 255;
    const int tile = blockIdx.x * (CPB * SC);
    const float t00 = trans[0], t01 = trans[1], t10 = trans[2], t11 = trans[3];
    const double Z = zptr[0];
    const float2* fv = (const float2*)feats;

    // P0: coalesced feats -> LDS (pos p -> lds[(p/SC)*LROW + 2*(p%SC)])
    #pragma unroll
    for (int k = 0; k < SC; ++k) {
        int p = k * CPB + t;
        float2 f = fv[tile + p];
        int cc = p >> 4, ii = p & 15;
        lds[cc * LROW + 2 * ii]     = f.x;
        lds[cc * LROW + 2 * ii + 1] = f.y;
    }

    // boundary vectors (f64, one-shot)
    double2 gs = gstart[g], ge = gend[g];
    double2 v, w;
    if (r == 0) {
        v = gs;
    } else {
        FMat P = PF[c - 1];
        v = make_double2(lse2d((double)P.m00 + gs.x, (double)P.m01 + gs.y),
                         lse2d((double)P.m10 + gs.x, (double)P.m11 + gs.y));
    }
    if (r == 255) {
        w = ge;
    } else {
        FMat Tm = SB[c + 1];
        w = make_double2(lse2d((double)Tm.m00 + ge.x, (double)Tm.m01 + ge.y),
                         lse2d((double)Tm.m10 + ge.x, (double)Tm.m11 + ge.y));
    }
    __syncthreads();

    const float* myrow = lds + t * LROW;
    float* myroww = lds + t * LROW;

    // PA: beta backward, fp32 relative to wbase
    const double wbase = w.x;
    float w0 = 0.0f, w1 = (float)(w.y - wbase);
    float bx[SC], by[SC];
    bx[SC - 1] = w0; by[SC - 1] = w1;
    #pragma unroll
    for (int k = SC - 2; k >= 0; --k) {
        float fx = myrow[2 * k], fy = myrow[2 * k + 1];
        float n0 = fx + lse2f(t00 + w0, t10 + w1);  // beta[0]
        float n1 = fy + lse2f(t01 + w0, t11 + w1);  // beta[1]
        w0 = n0; w1 = n1;
        bx[k] = w0; by[k] = w1;
    }

    // PB: alpha forward fp32 relative + combine
    const double vbase = v.x;
    float a0 = 0.0f, a1 = (float)(v.y - vbase);
    const float cbase = (float)((vbase + wbase) - Z);
    #pragma unroll
    for (int k = 0; k < SC; ++k) {
        float fx = myrow[2 * k], fy = myrow[2 * k + 1];
        if (k > 0) {
            float n0 = fx + lse2f(t00 + a0, t01 + a1);
            float n1 = fy + lse2f(t10 + a0, t11 + a1);
            a0 = n0; a1 = n1;
        }
        float m0 = cbase + a0 + bx[k] - fx;
        float m1 = cbase + a1 + by[k] - fy;
        myroww[2 * k]     = __expf(m0);
        myroww[2 * k + 1] = __expf(m1);
    }
    __syncthreads();

    // PC: coalesced store LDS -> out
    float2* ov = (float2*)out;
    #pragma unroll
    for (int k = 0; k < SC; ++k) {
        int p = k * CPB + t;
        int cc = p >> 4, ii = p & 15;
        ov[tile + p] = make_float2(lds[cc * LROW + 2 * ii],
                                   lds[cc * LROW + 2 * ii + 1]);
    }
}

extern "C" void kernel_launch(void* const* d_in, const int* in_sizes, int n_in,
                              void* d_out, int out_size, void* d_ws, size_t ws_size,
                              hipStream_t stream)
{
    const float* feats = (const float*)d_in[0];
    const float* trans = (const float*)d_in[1];
    float* out = (float*)d_out;

    char* ws = (char*)d_ws;
    size_t off = 0;
    FMat* PF = (FMat*)(ws + off); off += (size_t)NC * sizeof(FMat);   // 4 MB
    FMat* SB = (FMat*)(ws + off); off += (size_t)NC * sizeof(FMat);   // 4 MB
    DMat* GF = (DMat*)(ws + off); off += (size_t)NG * sizeof(DMat);   // 32 KB
    DMat* GB = (DMat*)(ws + off); off += (size_t)NG * sizeof(DMat);   // 32 KB
    double2* gstart = (double2*)(ws + off); off += (size_t)NG * sizeof(double2);
    double2* gend   = (double2*)(ws + off); off += (size_t)NG * sizeof(double2);
    double*  zout   = (double*)(ws + off);

    hipLaunchKernelGGL(crf_k1, dim3(NC / CPB), dim3(CPB), 0, stream,
                       feats, trans, PF, SB, GF, GB);
    hipLaunchKernelGGL(crf_k2, dim3(2), dim3(K2_T), 0, stream,
                       feats, GF, GB, gstart, gend, zout);
    hipLaunchKernelGGL(crf_k3, dim3(NC / CPB), dim3(CPB), 0, stream,
                       feats, trans, PF, SB, gstart, gend, zout, out);
}